// Round 7
// baseline (73.212 us; speedup 1.0000x reference)
//
#include <hip/hip_runtime.h>

#define NB   16
#define NC   3
#define NH   512
#define NW   512
#define OUTH 506
#define OUTW 506
#define NCHK 42          // 40 chunks x 12 rows + 2 chunks x 13 rows = 506
#define WPB  4           // waves per block (256 threads)
#define NTASK (NB * NC * NCHK * 2)   // 4032 -> 1008 blocks (<= 1024 resident)

// -------- kernel 0: init workspace (runs every call; harness doesn't re-poison)
__global__ void ssim_init_ws(unsigned int* mn, unsigned int* mx, float* sum) {
    int i = threadIdx.x;
    if (i < NB) { mn[i] = 0x7f7fffffu; mx[i] = 0u; sum[i] = 0.0f; }
}

// -------- kernel 1: per-image min/max of pred (values >= 0 -> uint-bit order == float order)
__global__ __launch_bounds__(256) void ssim_minmax(const float* __restrict__ pred,
                                                   unsigned int* __restrict__ mn,
                                                   unsigned int* __restrict__ mx) {
    int b = blockIdx.y;
    const float4* p4 = (const float4*)(pred + (size_t)b * (NC * NH * NW));
    const int n4 = (NC * NH * NW) / 4;
    float lmin = 3.4e38f, lmax = -3.4e38f;
    for (int i = blockIdx.x * blockDim.x + threadIdx.x; i < n4; i += gridDim.x * blockDim.x) {
        float4 v = p4[i];
        lmin = fminf(lmin, fminf(fminf(v.x, v.y), fminf(v.z, v.w)));
        lmax = fmaxf(lmax, fmaxf(fmaxf(v.x, v.y), fmaxf(v.z, v.w)));
    }
    #pragma unroll
    for (int off = 32; off; off >>= 1) {
        lmin = fminf(lmin, __shfl_down(lmin, off, 64));
        lmax = fmaxf(lmax, __shfl_down(lmax, off, 64));
    }
    __shared__ float smin[4], smax[4];
    int wid = threadIdx.x >> 6, lane = threadIdx.x & 63;
    if (lane == 0) { smin[wid] = lmin; smax[wid] = lmax; }
    __syncthreads();
    if (threadIdx.x == 0) {
        float m = fminf(fminf(smin[0], smin[1]), fminf(smin[2], smin[3]));
        float M = fmaxf(fmaxf(smax[0], smax[1]), fmaxf(smax[2], smax[3]));
        atomicMin(&mn[b], __float_as_uint(m));
        atomicMax(&mx[b], __float_as_uint(M));
    }
}

// -------- kernel 2: register-resident separable sliding-window SSIM
// Same task geometry as R6 (4032 wave-tasks, 1008 blocks). ONE change:
// rolled steady-state loop instead of full 18-iter unroll, so the hot code
// is a few KB (I$-resident) instead of ~40KB of straight-line instructions.
__global__ __launch_bounds__(256) void ssim_main(const float* __restrict__ tin,
                                                 const float* __restrict__ pin,
                                                 const unsigned int* __restrict__ mn,
                                                 const unsigned int* __restrict__ mx,
                                                 float* __restrict__ sum) {
    const int warp  = threadIdx.x >> 6;
    const int lane  = threadIdx.x & 63;
    const int wid   = blockIdx.x * WPB + warp;
    const int imgch = wid / (NCHK * 2);
    const int rem   = wid - imgch * (NCHK * 2);
    const int chunk = rem >> 1;
    const int half  = rem & 1;
    const int b     = imgch / NC;
    const int r0    = chunk * 12 + max(0, chunk - 40);   // chunks 40,41 have 13 rows
    const int kend  = (chunk >= 40) ? 19 : 18;
    const int c0    = half * 256 + lane * 4;

    const float* tb = tin + (size_t)imgch * (NH * NW) + (size_t)r0 * NW;
    const float* pb = pin + (size_t)imgch * (NH * NW) + (size_t)r0 * NW;

    const float dr  = __uint_as_float(mx[b]) - __uint_as_float(mn[b]);
    const float c1  = (0.01f * dr) * (0.01f * dr);
    const float c2  = (0.03f * dr) * (0.03f * dr);
    const float C1s = 2401.0f * c1;   // 49^2 * c1
    const float C2s = 2352.0f * c2;   // 48*49 * c2

    // clamped bases; clamps bite only for half=1 lanes 62-63 whose affected
    // tracked slots feed exclusively masked (>= OUTW) outputs
    const int cb0 = c0;                   // <= 508 = NW-4, in bounds
    const int cb1 = min(c0 + 4, NW - 4);
    const int cb2 = min(c0 + 8, NW - 2);  // float2 load (cols c0+8, c0+9)

    float st[10], sp[10], stt[10], spp[10], stp[10];
    #pragma unroll
    for (int i = 0; i < 10; ++i) { st[i]=0.f; sp[i]=0.f; stt[i]=0.f; spp[i]=0.f; stp[i]=0.f; }

    float acc = 0.f;

#define UPD1(I, T_, P_, SGN) do {                                   \
        float _t = (T_), _p = (P_);                                 \
        st[I]  += SGN _t;  sp[I]  += SGN _p;                        \
        stt[I] = fmaf(SGN _t, _t, stt[I]);                          \
        spp[I] = fmaf(SGN _p, _p, spp[I]);                          \
        stp[I] = fmaf(SGN _t, _p, stp[I]);                          \
    } while (0)

#define LOADROW(DT, DP, RT, RP) do {                                \
        *(float4*)&DT[0] = *(const float4*)((RT) + cb0);            \
        *(float4*)&DT[4] = *(const float4*)((RT) + cb1);            \
        *(float2*)&DT[8] = *(const float2*)((RT) + cb2);            \
        *(float4*)&DP[0] = *(const float4*)((RP) + cb0);            \
        *(float4*)&DP[4] = *(const float4*)((RP) + cb1);            \
        *(float2*)&DP[8] = *(const float2*)((RP) + cb2);            \
    } while (0)

#define APPLY(VT, VP, SGN) do {                                     \
        _Pragma("unroll")                                           \
        for (int i = 0; i < 10; ++i) UPD1(i, VT[i], VP[i], SGN);    \
    } while (0)

#define SSIMADD(C) do {                                             \
        if (c0 + (C) < OUTW) {                                      \
            float p12 = S1 * S2;                                    \
            float q1  = S1 * S1, q2 = S2 * S2;                      \
            float A1  = fmaf(2.f, p12, C1s);                        \
            float B1  = q1 + q2 + C1s;                              \
            float mtp = fmaf(49.f, S5, -p12);                       \
            float A2  = fmaf(2.f, mtp, C2s);                        \
            float mtt = fmaf(49.f, S3, -q1);                        \
            float mpp = fmaf(49.f, S4, -q2);                        \
            float B2  = mtt + mpp + C2s;                            \
            acc += __fdividef(A1 * A2, B1 * B2);                    \
        }                                                           \
    } while (0)

#define EMIT do {                                                   \
        float S1 = st[0]+st[1]+st[2]+st[3]+st[4]+st[5]+st[6];       \
        float S2 = sp[0]+sp[1]+sp[2]+sp[3]+sp[4]+sp[5]+sp[6];       \
        float S3 = stt[0]+stt[1]+stt[2]+stt[3]+stt[4]+stt[5]+stt[6];\
        float S4 = spp[0]+spp[1]+spp[2]+spp[3]+spp[4]+spp[5]+spp[6];\
        float S5 = stp[0]+stp[1]+stp[2]+stp[3]+stp[4]+stp[5]+stp[6];\
        SSIMADD(0);                                                 \
        _Pragma("unroll")                                           \
        for (int c = 1; c < 4; ++c) {                               \
            S1 += st[c+6]  - st[c-1];                               \
            S2 += sp[c+6]  - sp[c-1];                               \
            S3 += stt[c+6] - stt[c-1];                              \
            S4 += spp[c+6] - spp[c-1];                              \
            S5 += stp[c+6] - stp[c-1];                              \
            SSIMADD(c);                                             \
        }                                                           \
    } while (0)

    // prologue rows 0..5: accumulate only (fully unrolled, loads hoistable)
    {
        #pragma unroll
        for (int k = 0; k < 6; ++k) {
            float eT[10], eP[10];
            LOADROW(eT, eP, tb + k * NW, pb + k * NW);
            APPLY(eT, eP, +);
        }
    }
    // row 6: first emit
    {
        float eT[10], eP[10];
        LOADROW(eT, eP, tb + 6 * NW, pb + 6 * NW);
        APPLY(eT, eP, +);
        EMIT;
    }
    // steady state: rolled (I$-resident), loads issued at iteration top
    #pragma unroll 2
    for (int k = 7; k < kend; ++k) {
        float eT[10], eP[10], lT[10], lP[10];
        const float* trow = tb + k * NW;
        const float* prow = pb + k * NW;
        LOADROW(lT, lP, trow - 7 * NW, prow - 7 * NW);
        LOADROW(eT, eP, trow, prow);
        APPLY(eT, eP, +);
        APPLY(lT, lP, -);
        EMIT;
    }

#undef EMIT
#undef SSIMADD
#undef APPLY
#undef LOADROW
#undef UPD1

    #pragma unroll
    for (int off = 32; off; off >>= 1) acc += __shfl_down(acc, off, 64);
    __shared__ float part[WPB];
    if (lane == 0) part[warp] = acc;
    __syncthreads();
    // all 4 waves of a block share the same image (84 wids per imgch, 4 | 84)
    if (threadIdx.x == 0)
        atomicAdd(&sum[b], part[0] + part[1] + part[2] + part[3]);
}

// -------- kernel 3: finalize mean
__global__ void ssim_finalize(const float* __restrict__ sum, float* __restrict__ out) {
    int i = threadIdx.x;
    if (i < NB) out[i] = sum[i] / (float)(NC * OUTH * OUTW);
}

extern "C" void kernel_launch(void* const* d_in, const int* in_sizes, int n_in,
                              void* d_out, int out_size, void* d_ws, size_t ws_size,
                              hipStream_t stream) {
    const float* t = (const float*)d_in[0];   // true
    const float* p = (const float*)d_in[1];   // pred
    float* out = (float*)d_out;

    unsigned int* mn  = (unsigned int*)d_ws;
    unsigned int* mx  = mn + NB;
    float*        sum = (float*)(mx + NB);

    ssim_init_ws<<<1, 64, 0, stream>>>(mn, mx, sum);
    ssim_minmax<<<dim3(64, NB), 256, 0, stream>>>(p, mn, mx);

    // 4032 wave-tasks (16 img x 3 ch x 42 chunks x 2 col-halves), 4 waves/block
    ssim_main<<<dim3(NTASK / WPB), 256, 0, stream>>>(t, p, mn, mx, sum);

    ssim_finalize<<<1, 64, 0, stream>>>(sum, out);
}

// Round 8
// 64.515 us; speedup vs baseline: 1.1348x; 1.1348x over previous
//
#include <hip/hip_runtime.h>

#define NB   16
#define NC   3
#define NH   512
#define NW   512
#define OUTH 506
#define OUTW 506
#define NCHK 21          // 19 chunks x 24 rows + 2 chunks x 25 rows = 506
#define NSLOT 9          // LDS ring slots (see race analysis in comments)
#define NBLK (NB * NC * NCHK)   // 1008 blocks

// -------- kernel 0: init workspace (runs every call; harness doesn't re-poison)
__global__ void ssim_init_ws(unsigned int* mn, unsigned int* mx, float* sum) {
    int i = threadIdx.x;
    if (i < NB) { mn[i] = 0x7f7fffffu; mx[i] = 0u; sum[i] = 0.0f; }
}

// -------- kernel 1: per-image min/max of pred (values >= 0 -> uint-bit order == float order)
__global__ __launch_bounds__(256) void ssim_minmax(const float* __restrict__ pred,
                                                   unsigned int* __restrict__ mn,
                                                   unsigned int* __restrict__ mx) {
    int b = blockIdx.y;
    const float4* p4 = (const float4*)(pred + (size_t)b * (NC * NH * NW));
    const int n4 = (NC * NH * NW) / 4;
    float lmin = 3.4e38f, lmax = -3.4e38f;
    for (int i = blockIdx.x * blockDim.x + threadIdx.x; i < n4; i += gridDim.x * blockDim.x) {
        float4 v = p4[i];
        lmin = fminf(lmin, fminf(fminf(v.x, v.y), fminf(v.z, v.w)));
        lmax = fmaxf(lmax, fmaxf(fmaxf(v.x, v.y), fmaxf(v.z, v.w)));
    }
    #pragma unroll
    for (int off = 32; off; off >>= 1) {
        lmin = fminf(lmin, __shfl_down(lmin, off, 64));
        lmax = fmaxf(lmax, __shfl_down(lmax, off, 64));
    }
    __shared__ float smin[4], smax[4];
    int wid = threadIdx.x >> 6, lane = threadIdx.x & 63;
    if (lane == 0) { smin[wid] = lmin; smax[wid] = lmax; }
    __syncthreads();
    if (threadIdx.x == 0) {
        float m = fminf(fminf(smin[0], smin[1]), fminf(smin[2], smin[3]));
        float M = fmaxf(fmaxf(smax[0], smax[1]), fmaxf(smax[2], smax[3]));
        atomicMin(&mn[b], __float_as_uint(m));
        atomicMax(&mx[b], __float_as_uint(M));
    }
}

// -------- kernel 2: LDS-ring separable sliding-window SSIM
// Block = 4 waves = one (imgch, row-chunk), all 512 cols. Each input row is
// loaded from global ONCE per block into a 9-slot LDS ring; the 7-row window
// history (enter + leave reads, column halo) is served from LDS.
// Thread li owns output cols {2li, 2li+1}, tracks vertical sums for 8 cols.
//
// Ring race analysis (1 barrier/iter, 1-row-ahead staging, N=9):
//   iter k: reads slots k%9 (enter) and (k-7)%9 == (k+2)%9 (leave),
//           writes slot (k+1)%9  -> disjoint from both reads.
//   slot of row k+1 last held row k-8, whose final read (leave) was iter k-1,
//   separated from the write by the end-of-iter-(k-1) barrier.
__global__ __launch_bounds__(256) void ssim_main(const float* __restrict__ tin,
                                                 const float* __restrict__ pin,
                                                 const unsigned int* __restrict__ mn,
                                                 const unsigned int* __restrict__ mx,
                                                 float* __restrict__ sum) {
    __shared__ float ring[NSLOT][2][NW];   // 36,864 B -> 4 blocks/CU
    __shared__ float part[4];

    const int li    = threadIdx.x;
    const int imgch = blockIdx.x / NCHK;
    const int chunk = blockIdx.x - imgch * NCHK;
    const int b     = imgch / NC;
    const int r0    = chunk * 24 + max(0, chunk - 19);  // chunks 19,20 have 25 rows
    const int rpc   = (chunk >= 19) ? 25 : 24;
    const int kend  = rpc + 6;

    const float* tbase = tin + (size_t)imgch * (NH * NW) + (size_t)r0 * NW;
    const float* pbase = pin + (size_t)imgch * (NH * NW) + (size_t)r0 * NW;

    const float dr  = __uint_as_float(mx[b]) - __uint_as_float(mn[b]);
    const float c1  = (0.01f * dr) * (0.01f * dr);
    const float c2  = (0.03f * dr) * (0.03f * dr);
    const float C1s = 2401.0f * c1;   // 49^2 * c1
    const float C2s = 2352.0f * c2;   // 48*49 * c2

    // staging role: waves 0-1 stage the t row, waves 2-3 the p row (float4 each)
    const int  sarr = (li < 128) ? 0 : 1;
    const int  scol = (li < 128) ? 4 * li : 4 * (li - 128);
    const float* gsrc = (sarr == 0) ? (tbase + scol) : (pbase + scol);

    // read-column base; threads 253-255 clamp (their outputs are masked, the
    // clamped reads just duplicate valid in-range data)
    const int rc = 2 * min(li, 252);
    const bool valid = (li < 253);

    float st[8], sp[8], stt[8], spp[8], stp[8];
    #pragma unroll
    for (int i = 0; i < 8; ++i) { st[i]=0.f; sp[i]=0.f; stt[i]=0.f; spp[i]=0.f; stp[i]=0.f; }

    float acc = 0.f;

    // prologue: stage row 0 into slot 0
    {
        float4 g = *(const float4*)gsrc;
        *(float4*)&ring[0][sarr][scol] = g;
    }
    __syncthreads();

    int se = 0;   // slot of enter row (k % 9)

#define SSIMADD do {                                                \
        float p12 = S1 * S2;                                        \
        float q1  = S1 * S1, q2 = S2 * S2;                          \
        float A1  = fmaf(2.f, p12, C1s);                            \
        float B1  = q1 + q2 + C1s;                                  \
        float mtp = fmaf(49.f, S5, -p12);                           \
        float A2  = fmaf(2.f, mtp, C2s);                            \
        float mtt = fmaf(49.f, S3, -q1);                            \
        float mpp = fmaf(49.f, S4, -q2);                            \
        float B2  = mtt + mpp + C2s;                                \
        acc += __fdividef(A1 * A2, B1 * B2);                        \
    } while (0)

    for (int k = 0; k < kend; ++k) {
        // 1) issue next-row global load early (latency hides under compute)
        float4 g;
        const bool more = (k + 1 < kend);
        if (more) g = *(const float4*)(gsrc + (size_t)(k + 1) * NW);

        // 2) enter: add row k (slot se) to vertical sums
        {
            #pragma unroll
            for (int j = 0; j < 4; ++j) {
                float2 a = *(const float2*)&ring[se][0][rc + 2 * j];
                float2 c = *(const float2*)&ring[se][1][rc + 2 * j];
                int i0 = 2 * j;
                st[i0]     += a.x;  sp[i0]     += c.x;
                stt[i0]     = fmaf(a.x, a.x, stt[i0]);
                spp[i0]     = fmaf(c.x, c.x, spp[i0]);
                stp[i0]     = fmaf(a.x, c.x, stp[i0]);
                st[i0 + 1] += a.y;  sp[i0 + 1] += c.y;
                stt[i0 + 1] = fmaf(a.y, a.y, stt[i0 + 1]);
                spp[i0 + 1] = fmaf(c.y, c.y, spp[i0 + 1]);
                stp[i0 + 1] = fmaf(a.y, c.y, stp[i0 + 1]);
            }
        }

        // 3) leave: subtract row k-7 (slot (k+2)%9 == se+2 mod 9)
        if (k >= 7) {
            int sl = se + 2; if (sl >= NSLOT) sl -= NSLOT;
            #pragma unroll
            for (int j = 0; j < 4; ++j) {
                float2 a = *(const float2*)&ring[sl][0][rc + 2 * j];
                float2 c = *(const float2*)&ring[sl][1][rc + 2 * j];
                int i0 = 2 * j;
                st[i0]     -= a.x;  sp[i0]     -= c.x;
                stt[i0]     = fmaf(-a.x, a.x, stt[i0]);
                spp[i0]     = fmaf(-c.x, c.x, spp[i0]);
                stp[i0]     = fmaf(-a.x, c.x, stp[i0]);
                st[i0 + 1] -= a.y;  sp[i0 + 1] -= c.y;
                stt[i0 + 1] = fmaf(-a.y, a.y, stt[i0 + 1]);
                spp[i0 + 1] = fmaf(-c.y, c.y, spp[i0 + 1]);
                stp[i0 + 1] = fmaf(-a.y, c.y, stp[i0 + 1]);
            }
        }

        // 4) emit 2 output pixels (cols 2li, 2li+1) for row r0+k-6
        if (k >= 6 && valid) {
            float S1 = st[0]+st[1]+st[2]+st[3]+st[4]+st[5]+st[6];
            float S2 = sp[0]+sp[1]+sp[2]+sp[3]+sp[4]+sp[5]+sp[6];
            float S3 = stt[0]+stt[1]+stt[2]+stt[3]+stt[4]+stt[5]+stt[6];
            float S4 = spp[0]+spp[1]+spp[2]+spp[3]+spp[4]+spp[5]+spp[6];
            float S5 = stp[0]+stp[1]+stp[2]+stp[3]+stp[4]+stp[5]+stp[6];
            SSIMADD;
            S1 += st[7]  - st[0];
            S2 += sp[7]  - sp[0];
            S3 += stt[7] - stt[0];
            S4 += spp[7] - spp[0];
            S5 += stp[7] - stp[0];
            SSIMADD;
        }

        // 5) write the staged row into slot (k+1)%9 (write-late: vmcnt dep here)
        if (more) {
            int sw = se + 1; if (sw >= NSLOT) sw -= NSLOT;
            *(float4*)&ring[sw][sarr][scol] = g;
        }

        // 6) one barrier per iter orders ring reuse across waves
        __syncthreads();
        if (++se == NSLOT) se = 0;
    }

#undef SSIMADD

    #pragma unroll
    for (int off = 32; off; off >>= 1) acc += __shfl_down(acc, off, 64);
    if ((li & 63) == 0) part[li >> 6] = acc;
    __syncthreads();
    if (li == 0)
        atomicAdd(&sum[b], part[0] + part[1] + part[2] + part[3]);
}

// -------- kernel 3: finalize mean
__global__ void ssim_finalize(const float* __restrict__ sum, float* __restrict__ out) {
    int i = threadIdx.x;
    if (i < NB) out[i] = sum[i] / (float)(NC * OUTH * OUTW);
}

extern "C" void kernel_launch(void* const* d_in, const int* in_sizes, int n_in,
                              void* d_out, int out_size, void* d_ws, size_t ws_size,
                              hipStream_t stream) {
    const float* t = (const float*)d_in[0];   // true
    const float* p = (const float*)d_in[1];   // pred
    float* out = (float*)d_out;

    unsigned int* mn  = (unsigned int*)d_ws;
    unsigned int* mx  = mn + NB;
    float*        sum = (float*)(mx + NB);

    ssim_init_ws<<<1, 64, 0, stream>>>(mn, mx, sum);
    ssim_minmax<<<dim3(64, NB), 256, 0, stream>>>(p, mn, mx);

    // 1008 blocks (16 img x 3 ch x 21 row-chunks), 4 waves/block, 36 KB LDS
    ssim_main<<<dim3(NBLK), 256, 0, stream>>>(t, p, mn, mx, sum);

    ssim_finalize<<<1, 64, 0, stream>>>(sum, out);
}